// Round 2
// baseline (783.696 us; speedup 1.0000x reference)
//
#include <hip/hip_runtime.h>
#include <hip/hip_bf16.h>
#include <stdint.h>

// Problem dims (fixed by reference): B,C,F,W,H,K,S = 64,256,512,64,64,3,1
#define C_DIM 256
#define F_DIM 512
#define B_DIM 64
#define N_DIM 4096          // W*H
#define BN 128              // n per block (one b, one n-tile per block)
#define BF 128              // f per f-tile (4 f-tiles looped inside block)

typedef __bf16  bf16x8 __attribute__((ext_vector_type(8)));
typedef float   f32x4  __attribute__((ext_vector_type(4)));

// ---------------- prep: W2[f][c] = sum_{3x3} tanh(w + 0.5*log(eps/(1-eps))) ----------------
// tanh(w + 0.5*ln r) = (e^{2w} r - 1)/(e^{2w} r + 1) = 1 - 2/(e^{2w} r + 1); inf-safe form.
__global__ void prep_w2(const float* __restrict__ w, const float* __restrict__ eps,
                        __hip_bfloat16* __restrict__ w2) {
    int id = blockIdx.x * blockDim.x + threadIdx.x;          // [0, F*C)
    if (id >= F_DIM * C_DIM) return;
    const float* wp = w  + id * 9;
    const float* ep = eps + id * 9;
    float s = 0.f;
#pragma unroll
    for (int i = 0; i < 9; ++i) {
        float wi = wp[i], e = ep[i];
        float r = e / (1.0f - e);
        float t = __expf(2.0f * wi) * r;
        s += 1.0f - 2.0f / (t + 1.0f);
    }
    w2[id] = __float2bfloat16(s);
}

__device__ inline uint32_t pack_bf16x2(float a, float b) {
    union { __hip_bfloat162 h; uint32_t u; } c;
    c.h.x = __float2bfloat16(a);
    c.h.y = __float2bfloat16(b);
    return c.u;
}

// ---------------- GEMM: out[b][f][n] = sum_c W2[f][c] * X[b][c][n] ----------------
// One block per (b, n-tile). X tile staged to LDS once (bf16, XOR-swizzled, c-halves
// pipelined against first compute steps). A (W2, 256 KB total -> L2-resident) is
// loaded DIRECTLY global->register per fragment: no sA, no per-step barriers at all.
__global__ __launch_bounds__(512, 4)
void gemm_kernel(const float* __restrict__ X,
                 const __hip_bfloat16* __restrict__ W2,
                 float* __restrict__ Out) {
    // sX: [n][c] bf16, 512B rows, col-bytes XOR'd with ((n&31)<<4)  -> 64 KB
    __shared__ unsigned char sX[BN * 512];

    const int tid  = threadIdx.x;
    const int lane = tid & 63;
    const int wave = tid >> 6;
    const int l15  = lane & 15;
    const int l4   = lane >> 4;

    const int bi = blockIdx.x >> 5;          // batch  [0,64)
    const int ni = blockIdx.x & 31;          // n-tile [0,32)

    const float* Xb = X   + (size_t)bi * C_DIM * N_DIM + ni * BN;
    float*       Ob = Out + (size_t)bi * F_DIM * N_DIM + ni * BN;

    // ---- staging thread map: n lane-consecutive (coalesced 256B), c chunk per tid>>7 ----
    const int sn = tid & 127;
    const int sc = (tid >> 7) * 32;          // c base within a 128-c half
    unsigned char* sbase = sX + sn * 512;
    const int sw = (sn & 31) << 4;
    const float* xp = Xb + sn;

    // ---- LO half (c in [0,128)): load -> pack -> swizzled b128 writes ----
    float vlo[4][8];
#pragma unroll
    for (int g = 0; g < 4; ++g) {
        const int c0 = sc + g * 8;
#pragma unroll
        for (int r = 0; r < 8; ++r)
            vlo[g][r] = __builtin_nontemporal_load(xp + (size_t)(c0 + r) * N_DIM);
    }
#pragma unroll
    for (int g = 0; g < 4; ++g) {
        const int c0 = sc + g * 8;
        uint4 pk;
        pk.x = pack_bf16x2(vlo[g][0], vlo[g][1]);
        pk.y = pack_bf16x2(vlo[g][2], vlo[g][3]);
        pk.z = pack_bf16x2(vlo[g][4], vlo[g][5]);
        pk.w = pack_bf16x2(vlo[g][6], vlo[g][7]);
        *(uint4*)(sbase + ((c0 * 2) ^ sw)) = pk;
    }

    // ---- issue HI loads (c in [128,256)) BEFORE the barrier: register loads
    // survive __syncthreads (no vmcnt-drain for plain loads); their ~900cyc HBM
    // latency hides under the first 4 k-steps of compute. ----
    float vhi[4][8];
#pragma unroll
    for (int g = 0; g < 4; ++g) {
        const int c0 = 128 + sc + g * 8;
#pragma unroll
        for (int r = 0; r < 8; ++r)
            vhi[g][r] = __builtin_nontemporal_load(xp + (size_t)(c0 + r) * N_DIM);
    }

    __syncthreads();   // LO half visible to all waves

    const int wm = (wave >> 1) * 32;         // wave tile: 32 f x 64 n
    const int wn = (wave & 1) * 64;

    f32x4 acc[2][4];
#pragma unroll
    for (int mi = 0; mi < 2; ++mi)
#pragma unroll
        for (int nj = 0; nj < 4; ++nj)
            acc[mi][nj] = (f32x4){0.f, 0.f, 0.f, 0.f};

    // one k-step: kq indexes a 32-c window; A-frags straight from global (L2-hot)
    auto step = [&](const __hip_bfloat16* Aw, int kq) {
        bf16x8 a0 = *(const bf16x8*)(Aw + kq * 32);
        bf16x8 a1 = *(const bf16x8*)(Aw + 16 * C_DIM + kq * 32);
        bf16x8 b[4];
#pragma unroll
        for (int nj = 0; nj < 4; ++nj) {
            const int nn  = wn + nj * 16 + l15;
            const int col = (kq * 64 + l4 * 16) ^ ((nn & 31) << 4);
            b[nj] = *(const bf16x8*)(sX + nn * 512 + col);
        }
#pragma unroll
        for (int nj = 0; nj < 4; ++nj) {
            acc[0][nj] = __builtin_amdgcn_mfma_f32_16x16x32_bf16(a0, b[nj], acc[0][nj], 0, 0, 0);
            acc[1][nj] = __builtin_amdgcn_mfma_f32_16x16x32_bf16(a1, b[nj], acc[1][nj], 0, 0, 0);
        }
    };

    // epilogue: C/D layout col=lane&15, row=(lane>>4)*4+r (m89-verified); resets acc
    auto epilogue = [&](int ft) {
        float* Oft = Ob + (size_t)(ft * BF) * N_DIM;
#pragma unroll
        for (int mi = 0; mi < 2; ++mi) {
            const int mrow = wm + mi * 16 + l4 * 4;
#pragma unroll
            for (int nj = 0; nj < 4; ++nj) {
                const int ncol = wn + nj * 16 + l15;
                float* op = Oft + (size_t)mrow * N_DIM + ncol;
#pragma unroll
                for (int r = 0; r < 4; ++r)
                    __builtin_nontemporal_store(acc[mi][nj][r], op + (size_t)r * N_DIM);
                acc[mi][nj] = (f32x4){0.f, 0.f, 0.f, 0.f};
            }
        }
    };

    const __hip_bfloat16* AwBase = W2 + (size_t)(wm + l15) * C_DIM + l4 * 8;

    // ---- ft=0, LO half (kq 0..3) while HI loads are in flight ----
#pragma unroll
    for (int kq = 0; kq < 4; ++kq) step(AwBase, kq);

    // ---- pack + write HI half, then one barrier ----
#pragma unroll
    for (int g = 0; g < 4; ++g) {
        const int c0 = 128 + sc + g * 8;
        uint4 pk;
        pk.x = pack_bf16x2(vhi[g][0], vhi[g][1]);
        pk.y = pack_bf16x2(vhi[g][2], vhi[g][3]);
        pk.z = pack_bf16x2(vhi[g][4], vhi[g][5]);
        pk.w = pack_bf16x2(vhi[g][6], vhi[g][7]);
        *(uint4*)(sbase + ((c0 * 2) ^ sw)) = pk;
    }
    __syncthreads();   // HI half visible; LAST barrier in the kernel

    // ---- ft=0 rest, then ft=1..3: barrier-free (sX read-only, A from global) ----
#pragma unroll
    for (int kq = 4; kq < 8; ++kq) step(AwBase, kq);
    epilogue(0);

    for (int ft = 1; ft < 4; ++ft) {
        const __hip_bfloat16* Aw = AwBase + (size_t)ft * BF * C_DIM;
#pragma unroll
        for (int kq = 0; kq < 8; ++kq) step(Aw, kq);
        epilogue(ft);
    }
}

extern "C" void kernel_launch(void* const* d_in, const int* in_sizes, int n_in,
                              void* d_out, int out_size, void* d_ws, size_t ws_size,
                              hipStream_t stream) {
    const float* x   = (const float*)d_in[0];   // [64,256,64,64]
    const float* w   = (const float*)d_in[1];   // [512,256,3,3]
    const float* eps = (const float*)d_in[2];   // [1,512,256,3,3]
    float* out       = (float*)d_out;           // [1,64,512,64,64]
    __hip_bfloat16* w2 = (__hip_bfloat16*)d_ws; // 512*256 bf16 = 256 KB scratch

    prep_w2<<<dim3((F_DIM * C_DIM + 255) / 256), dim3(256), 0, stream>>>(w, eps, w2);
    gemm_kernel<<<dim3(B_DIM * 32), dim3(512), 0, stream>>>(x, w2, out);
}